// Round 18
// baseline (535.775 us; speedup 1.0000x reference)
//
#include <hip/hip_runtime.h>
#include <hip/hip_bf16.h>

#define BB 4
#define NN 10000
#define EE 320000
#define HH 8
#define NHQ 2                 // head halves
#define NRQ 2                 // src ranges per batch
#define SEGR (NN / NRQ)       // 5000 segments per range
#define NSLICE 16             // edge slices -> grid = 4*2*2*16 = 256 = 1 block/CU
#define ESL (EE / NSLICE)     // 20000 edges per slice
#define UU 4                  // edges batched per thread (MLP)
#define SCALE 16777216.0f     // 2^24 fixed-point
#define INVSC (1.0f / 16777216.0f)

typedef float f4 __attribute__((ext_vector_type(4)));
typedef short s8v __attribute__((ext_vector_type(8)));
typedef unsigned short u16x8 __attribute__((ext_vector_type(8)));

__device__ __forceinline__ unsigned short f2bf(float f) {
  unsigned int u = __float_as_uint(f);
  u += 0x7FFFu + ((u >> 16) & 1u);
  return (unsigned short)(u >> 16);
}
__device__ __forceinline__ float bf2f(unsigned short s) {
  return __uint_as_float(((unsigned int)s) << 16);
}
__device__ __forceinline__ unsigned int ordf(float f) {
  unsigned int u = __float_as_uint(f);
  return (u & 0x80000000u) ? ~u : (u | 0x80000000u);
}
__device__ __forceinline__ float unordf(unsigned int u) {
  unsigned int b = (u & 0x80000000u) ? (u & 0x7FFFFFFFu) : ~u;
  return __uint_as_float(b);
}
__device__ __forceinline__ void gload_lds16(const void* g, void* l) {
  __builtin_amdgcn_global_load_lds((const __attribute__((address_space(1))) void*)g,
                                   (__attribute__((address_space(3))) void*)l, 16, 0, 0);
}

// ------- W transpose + bf16 convert: Wt[n][k] = bf16(W[k][n]); also zeroes mxbuf -------
__global__ __launch_bounds__(256) void k_transpose(const float* __restrict__ W,
                                                   unsigned short* __restrict__ Wt,
                                                   unsigned int* __restrict__ mxbuf) {
  if (blockIdx.x == 0 && blockIdx.y == 0 && threadIdx.x < 16) mxbuf[threadIdx.x] = 0u;
  __shared__ float tile[64][65];
  const int n0 = blockIdx.x * 64, k0 = blockIdx.y * 64;
  for (int i = threadIdx.x; i < 4096; i += 256) {
    int kk = i >> 6, nn = i & 63;
    tile[kk][nn] = W[(size_t)(k0 + kk) * 256 + n0 + nn];
  }
  __syncthreads();
  for (int i = threadIdx.x; i < 4096; i += 256) {
    int nn = i >> 6, kk = i & 63;
    Wt[(size_t)(n0 + nn) * 256 + (k0 + kk)] = f2bf(tile[kk][nn]);
  }
}

// ------- x f32 -> bf16, pure streaming (exact cover: 2500 blocks * 512 thr * 8 elems) -------
__global__ __launch_bounds__(512) void k_cvt2(const float* __restrict__ x,
                                              unsigned short* __restrict__ xbf) {
  const int t = blockIdx.x * 512 + threadIdx.x;   // < 1,280,000
  const f4* in = (const f4*)(x + (size_t)t * 8);
  f4 v0 = in[0], v1 = in[1];
  u16x8 o;
  o[0] = f2bf(v0[0]); o[1] = f2bf(v0[1]); o[2] = f2bf(v0[2]); o[3] = f2bf(v0[3]);
  o[4] = f2bf(v1[0]); o[5] = f2bf(v1[1]); o[6] = f2bf(v1[2]); o[7] = f2bf(v1[3]);
  *(u16x8*)(xbf + (size_t)t * 8) = o;
}

// ---- GEMM v7: ALL of B (W^T, 128 KB bf16) staged ONCE per block; each wave owns
// ---- independent 16-row x 256-col strips; ONE vmcnt drain per strip (not per K-step);
// ---- zero inner barriers. LDS = 128K B + 4 waves x 8K A = 160 KB, grid 256 = 1/CU.
__global__ __launch_bounds__(256, 1) void k_gemm(const unsigned short* __restrict__ xbf,
                                                 const unsigned short* __restrict__ Wt,
                                                 const float* __restrict__ a,
                                                 float* __restrict__ wx,
                                                 unsigned short* __restrict__ ssbf,
                                                 unsigned short* __restrict__ sdbf,
                                                 unsigned int* __restrict__ mxbuf) {
  extern __shared__ char dyn2[];
  unsigned short* sBb = (unsigned short*)dyn2;   // [256 cols][32 chunks][8 bf16] = 131072 B
  char* sAb = dyn2 + 131072;                     // 4 waves * 8192 B
  const int tid = threadIdx.x;
  const int wv = tid >> 6;
  const int lane = tid & 63;
  const int fr = lane & 15;
  const int fg = lane >> 4;
  char* aw = sAb + wv * 8192;

  // stage B fully: 8192 16-B chunks; slot sc of col holds global chunk sc^(col&7)
#pragma unroll
  for (int it = 0; it < 32; ++it) {
    int q = it * 256 + tid;
    int col = q >> 5, sc = q & 31;
    gload_lds16(Wt + (size_t)col * 256 + ((sc ^ (col & 7)) << 3),
                (char*)sBb + it * 4096 + wv * 1024);
  }
  asm volatile("s_waitcnt vmcnt(0)" ::: "memory");
  __syncthreads();

  const float as0 = a[fr], as1 = a[16 + fr];
  const float ad0 = a[32 + fr], ad1 = a[48 + fr];
  const int gfr = (fr ^ (fr >> 2)) & 3;          // A read-side swizzle term

  for (int sp = blockIdx.x * 4 + wv; sp < 2500; sp += 1024) {
    // guard: prior strip's LDS reads done before overwriting A buffer
    asm volatile("s_waitcnt lgkmcnt(0)" ::: "memory");
    {
      const int r = lane >> 2;
      const int cc = (lane & 3) ^ ((r ^ (r >> 2)) & 3);
      const unsigned short* ag = xbf + (size_t)(sp * 16 + r) * 256 + cc * 8;
#pragma unroll
      for (int j = 0; j < 8; ++j)
        gload_lds16(ag + j * 32, aw + j * 1024);
    }
    asm volatile("s_waitcnt vmcnt(0)" ::: "memory");
    __builtin_amdgcn_sched_barrier(0);

    f4 acc[16] = {};
#pragma unroll
    for (int s0 = 0; s0 < 8; ++s0) {
      s8v afr = *(const s8v*)(aw + s0 * 1024 + (fr * 4 + (fg ^ gfr)) * 16);
#pragma unroll
      for (int n = 0; n < 16; ++n) {
        int col = n * 16 + fr;
        s8v bfr = *(const s8v*)((char*)sBb + col * 512 + (((4 * s0 + fg) ^ (fr & 7)) << 4));
        acc[n] = __builtin_amdgcn_mfma_f32_16x16x32_bf16(afr, bfr, acc[n], 0, 0, 0);
      }
    }
    // wx store: D[row][col], col = n*16+fr, row = fg*4+q
    const size_t rb = (size_t)sp * 16;
#pragma unroll
    for (int n = 0; n < 16; ++n) {
      int col = n * 16 + fr;
#pragma unroll
      for (int q = 0; q < 4; ++q)
        wx[(rb + fg * 4 + q) * 256 + col] = acc[n][q];
    }
    // fused scores: wave covers ALL 8 heads; head pair hp uses acc[4hp..4hp+3]
#pragma unroll
    for (int hp = 0; hp < 4; ++hp) {
      unsigned mp0 = 0u, mp1 = 0u, md0 = 0u, md1 = 0u;
#pragma unroll
      for (int q = 0; q < 4; ++q) {
        float p0 = acc[4 * hp][q] * as0 + acc[4 * hp + 1][q] * as1;
        float p1 = acc[4 * hp + 2][q] * as0 + acc[4 * hp + 3][q] * as1;
        float d0 = acc[4 * hp][q] * ad0 + acc[4 * hp + 1][q] * ad1;
        float d1 = acc[4 * hp + 2][q] * ad0 + acc[4 * hp + 3][q] * ad1;
#pragma unroll
        for (int m = 1; m <= 8; m <<= 1) {
          p0 += __shfl_xor(p0, m);
          p1 += __shfl_xor(p1, m);
          d0 += __shfl_xor(d0, m);
          d1 += __shfl_xor(d1, m);
        }
        mp0 = max(mp0, ordf(p0)); mp1 = max(mp1, ordf(p1));
        md0 = max(md0, ordf(d0)); md1 = max(md1, ordf(d1));
        if (fr == 0) {
          size_t row = rb + fg * 4 + q;
          ((unsigned*)ssbf)[row * 4 + hp] = (unsigned)f2bf(p0) | ((unsigned)f2bf(p1) << 16);
          ((unsigned*)sdbf)[row * 4 + hp] = (unsigned)f2bf(d0) | ((unsigned)f2bf(d1) << 16);
        }
      }
      mp0 = max(mp0, (unsigned)__shfl_xor((int)mp0, 16));
      mp0 = max(mp0, (unsigned)__shfl_xor((int)mp0, 32));
      mp1 = max(mp1, (unsigned)__shfl_xor((int)mp1, 16));
      mp1 = max(mp1, (unsigned)__shfl_xor((int)mp1, 32));
      md0 = max(md0, (unsigned)__shfl_xor((int)md0, 16));
      md0 = max(md0, (unsigned)__shfl_xor((int)md0, 32));
      md1 = max(md1, (unsigned)__shfl_xor((int)md1, 16));
      md1 = max(md1, (unsigned)__shfl_xor((int)md1, 32));
      if (lane == 0) {
        atomicMax(&mxbuf[2 * hp], mp0);
        atomicMax(&mxbuf[2 * hp + 1], mp1);
        atomicMax(&mxbuf[8 + 2 * hp], md0);
        atomicMax(&mxbuf[8 + 2 * hp + 1], md1);
      }
    }
  }
}

// ---- LDS-privatized denom binning: block = (batch, head-half, src-range, slice) ----
__global__ __launch_bounds__(1024) void k_bin(const int* __restrict__ edge,
                                              const unsigned short* __restrict__ ssbf,
                                              const unsigned short* __restrict__ sdbf,
                                              const unsigned int* __restrict__ mxbuf,
                                              unsigned int* __restrict__ partial) {
  extern __shared__ unsigned int ldsu[];
  unsigned int* hist = ldsu;                      // [4][SEGR] u32
  uint2* stg = (uint2*)(ldsu + 4 * SEGR);         // [SEGR] 8-B src half-rows
  const int blk = blockIdx.x;                     // ((b*2+hq)*2+rq)*NSLICE + r
  const int r = blk & (NSLICE - 1);
  const int c = blk / NSLICE;
  const int rq = c & 1;
  const int hq = (c >> 1) & 1;
  const int b = c >> 2;
  const int tid = threadIdx.x;
  const int lo = rq * SEGR;
  for (int i = tid; i < 4 * SEGR; i += 1024) hist[i] = 0u;
  const unsigned short* ssb = ssbf + ((size_t)b * NN + lo) * 8 + hq * 4;
  for (int i = tid; i < SEGR; i += 1024) stg[i] = *(const uint2*)(ssb + (size_t)i * 8);
  __syncthreads();
  float MH[4];
#pragma unroll
  for (int j = 0; j < 4; ++j)
    MH[j] = fmaxf(unordf(mxbuf[hq * 4 + j]) + unordf(mxbuf[8 + hq * 4 + j]), 0.f);
  const int* eps = edge + (size_t)b * 2 * EE + r * ESL;
  const int* epd = eps + EE;
  const unsigned short* sdb = sdbf + (size_t)b * NN * 8 + hq * 4;
  for (int base = 0; base < ESL; base += UU * 1024) {
    int ls4[UU], dst4[UU];
    bool v4[UU];
#pragma unroll
    for (int u = 0; u < UU; ++u) {
      int i = base + tid + u * 1024;
      bool inb = i < ESL;
      int s = inb ? eps[i] : 0;
      dst4[u] = inb ? epd[i] : 0;
      int ls = s - lo;
      v4[u] = inb && ((unsigned)ls < (unsigned)SEGR);
      ls4[u] = ls;
    }
    uint2 du4[UU];
#pragma unroll
    for (int u = 0; u < UU; ++u)
      if (v4[u]) du4[u] = *(const uint2*)(sdb + (size_t)dst4[u] * 8);
#pragma unroll
    for (int u = 0; u < UU; ++u) {
      if (v4[u]) {
        uint2 su = stg[ls4[u]];
        float t0 = __uint_as_float(su.x << 16) + __uint_as_float(du4[u].x << 16);
        float t1 = __uint_as_float(su.x & 0xFFFF0000u) + __uint_as_float(du4[u].x & 0xFFFF0000u);
        float t2 = __uint_as_float(su.y << 16) + __uint_as_float(du4[u].y << 16);
        float t3 = __uint_as_float(su.y & 0xFFFF0000u) + __uint_as_float(du4[u].y & 0xFFFF0000u);
        t0 = t0 >= 0.f ? t0 : 0.2f * t0;
        t1 = t1 >= 0.f ? t1 : 0.2f * t1;
        t2 = t2 >= 0.f ? t2 : 0.2f * t2;
        t3 = t3 >= 0.f ? t3 : 0.2f * t3;
        atomicAdd(&hist[0 * SEGR + ls4[u]], (unsigned)(__expf(t0 - MH[0]) * SCALE + 0.5f));
        atomicAdd(&hist[1 * SEGR + ls4[u]], (unsigned)(__expf(t1 - MH[1]) * SCALE + 0.5f));
        atomicAdd(&hist[2 * SEGR + ls4[u]], (unsigned)(__expf(t2 - MH[2]) * SCALE + 0.5f));
        atomicAdd(&hist[3 * SEGR + ls4[u]], (unsigned)(__expf(t3 - MH[3]) * SCALE + 0.5f));
      }
    }
  }
  __syncthreads();
  f4* pout = (f4*)(partial + (size_t)blk * (4 * SEGR));
  const f4* lin = (const f4*)hist;
  for (int i = tid; i < SEGR; i += 1024) pout[i] = lin[i];
}

// ---- reduce NSLICE slice-partials (u32) -> denom (bf16 half-rows), exact int sums ----
__global__ __launch_bounds__(256) void k_reduce(const unsigned int* __restrict__ partial,
                                                unsigned short* __restrict__ dnbf) {
  const int t = blockIdx.x * 256 + threadIdx.x;   // BB*NHQ*NRQ*SEGR = 80000
  if (t >= BB * NHQ * NRQ * SEGR) return;
  const int ls = t % SEGR;
  const int c = t / SEGR;                         // ((b*2+hq)*2+rq)
  const unsigned int* pp = partial + (size_t)c * NSLICE * (4 * SEGR);
  unsigned long long s[4] = {0, 0, 0, 0};
#pragma unroll 4
  for (int r = 0; r < NSLICE; ++r)
#pragma unroll
    for (int h = 0; h < 4; ++h)
      s[h] += pp[(size_t)r * (4 * SEGR) + h * SEGR + ls];
  const int rq = c & 1, hq = (c >> 1) & 1, b = c >> 2;
  uint2 pk;
  pk.x = (unsigned)f2bf((float)s[0] * INVSC) | ((unsigned)f2bf((float)s[1] * INVSC) << 16);
  pk.y = (unsigned)f2bf((float)s[2] * INVSC) | ((unsigned)f2bf((float)s[3] * INVSC) << 16);
  *(uint2*)(dnbf + ((size_t)b * NN + rq * SEGR + ls) * 8 + hq * 4) = pk;
}

// ---------------- finalize: att = exp(el - M) / denom ----------------
__global__ __launch_bounds__(256) void k_fin(const int* __restrict__ edge,
                                             const unsigned short* __restrict__ ssbf,
                                             const unsigned short* __restrict__ sdbf,
                                             const unsigned short* __restrict__ dnbf,
                                             const unsigned int* __restrict__ mxbuf,
                                             float* __restrict__ att) {
  const int idx = blockIdx.x * 256 + threadIdx.x;
  const int b = idx / EE;
  const int e = idx - b * EE;
  const int src = edge[(size_t)b * 2 * EE + e];
  const int dst = edge[(size_t)b * 2 * EE + EE + e];
  const size_t seg = (size_t)b * NN + src;
  float MM[8];
#pragma unroll
  for (int j = 0; j < 8; ++j)
    MM[j] = fmaxf(unordf(mxbuf[j]) + unordf(mxbuf[8 + j]), 0.f);
  u16x8 ss = *(const u16x8*)(ssbf + seg * 8);
  u16x8 sd = *(const u16x8*)(sdbf + ((size_t)b * NN + dst) * 8);
  u16x8 dn = *(const u16x8*)(dnbf + seg * 8);
  f4 o0, o1;
#pragma unroll
  for (int j = 0; j < 4; ++j) {
    float t0 = bf2f(ss[j]) + bf2f(sd[j]);
    t0 = t0 >= 0.f ? t0 : 0.2f * t0;
    float t1 = bf2f(ss[4 + j]) + bf2f(sd[4 + j]);
    t1 = t1 >= 0.f ? t1 : 0.2f * t1;
    float n0 = __expf(t0 - MM[j]);
    float n1 = __expf(t1 - MM[4 + j]);
    o0[j] = n0 / fmaxf(bf2f(dn[j]), n0);
    o1[j] = n1 / fmaxf(bf2f(dn[4 + j]), n1);
  }
  f4* op = (f4*)(att + (size_t)idx * 8);
  op[0] = o0;
  op[1] = o1;
}

extern "C" void kernel_launch(void* const* d_in, const int* in_sizes, int n_in,
                              void* d_out, int out_size, void* d_ws, size_t ws_size,
                              hipStream_t stream) {
  const float* x = (const float*)d_in[0];
  const int* edge = (const int*)d_in[1];
  const float* W = (const float*)d_in[2];
  const float* a = (const float*)d_in[3];

  float* att = (float*)d_out;                       // (B,E,H) = 10,240,000 f32 = 40.96 MB
  float* wx = att + (size_t)BB * EE * HH;           // (B,N,256) = 10,240,000 f32

  // dead-region reuse inside att (40.96 MB):
  //   xbf     = att[5.12M .. 10.24M f32)  (20.48 MB) — written by k_cvt2, read by k_gemm
  //   partial = att[0 .. 5.12M f32)       (20.48 MB) — written by k_bin (after k_gemm)
  unsigned short* xbf = (unsigned short*)(att + 5120000);
  unsigned int* partial = (unsigned int*)att;

  char* ws = (char*)d_ws;
  unsigned short* Wt = (unsigned short*)ws;                 // 128 KiB
  unsigned short* ssbf = (unsigned short*)(ws + 131072);    // 320000 u16
  unsigned short* sdbf = ssbf + 320000;                     // 320000 u16
  unsigned short* dnbf = sdbf + 320000;                     // 320000 u16
  unsigned int* mxbuf = (unsigned int*)(dnbf + 320000);     // 16 u32

  const int gemmLds = 131072 + 4 * 8192;   // 160 KiB exactly
  hipFuncSetAttribute((const void*)k_gemm, hipFuncAttributeMaxDynamicSharedMemorySize, gemmLds);
  hipFuncSetAttribute((const void*)k_bin, hipFuncAttributeMaxDynamicSharedMemorySize,
                      4 * SEGR * 4 + SEGR * 8);

  k_transpose<<<dim3(4, 4), 256, 0, stream>>>(W, Wt, mxbuf);
  k_cvt2<<<2500, 512, 0, stream>>>(x, xbf);
  k_gemm<<<256, 256, gemmLds, stream>>>(xbf, Wt, a, wx, ssbf, sdbf, mxbuf);
  k_bin<<<BB * NHQ * NRQ * NSLICE, 1024, 4 * SEGR * 4 + SEGR * 8, stream>>>(edge, ssbf, sdbf, mxbuf, partial);
  k_reduce<<<(BB * NHQ * NRQ * SEGR + 255) / 256, 256, 0, stream>>>(partial, dnbf);
  k_fin<<<5000, 256, 0, stream>>>(edge, ssbf, sdbf, dnbf, mxbuf, att);
}

// Round 19
// 279.762 us; speedup vs baseline: 1.9151x; 1.9151x over previous
//
#include <hip/hip_runtime.h>
#include <hip/hip_bf16.h>

#define BB 4
#define NN 10000
#define EE 320000
#define HH 8
#define NHQ 2                 // head halves
#define NRQ 2                 // src ranges per batch
#define SEGR (NN / NRQ)       // 5000 segments per range
#define NSLICE 16             // edge slices -> grid = 4*2*2*16 = 256 = 1 block/CU
#define ESL (EE / NSLICE)     // 20000 edges per slice
#define UU 4                  // edges batched per thread (MLP)
#define SCALE 16777216.0f     // 2^24 fixed-point
#define INVSC (1.0f / 16777216.0f)

typedef float f4 __attribute__((ext_vector_type(4)));
typedef short s8v __attribute__((ext_vector_type(8)));
typedef unsigned short u16x8 __attribute__((ext_vector_type(8)));

__device__ __forceinline__ unsigned short f2bf(float f) {
  unsigned int u = __float_as_uint(f);
  u += 0x7FFFu + ((u >> 16) & 1u);
  return (unsigned short)(u >> 16);
}
__device__ __forceinline__ float bf2f(unsigned short s) {
  return __uint_as_float(((unsigned int)s) << 16);
}
__device__ __forceinline__ unsigned int ordf(float f) {
  unsigned int u = __float_as_uint(f);
  return (u & 0x80000000u) ? ~u : (u | 0x80000000u);
}
__device__ __forceinline__ float unordf(unsigned int u) {
  unsigned int b = (u & 0x80000000u) ? (u & 0x7FFFFFFFu) : ~u;
  return __uint_as_float(b);
}
__device__ __forceinline__ void gload_lds16(const void* g, void* l) {
  __builtin_amdgcn_global_load_lds((const __attribute__((address_space(1))) void*)g,
                                   (__attribute__((address_space(3))) void*)l, 16, 0, 0);
}

// ------- W transpose + bf16 convert: Wt[n][k] = bf16(W[k][n]); also zeroes mxbuf -------
__global__ __launch_bounds__(256) void k_transpose(const float* __restrict__ W,
                                                   unsigned short* __restrict__ Wt,
                                                   unsigned int* __restrict__ mxbuf) {
  if (blockIdx.x == 0 && blockIdx.y == 0 && threadIdx.x < 16) mxbuf[threadIdx.x] = 0u;
  __shared__ float tile[64][65];
  const int n0 = blockIdx.x * 64, k0 = blockIdx.y * 64;
  for (int i = threadIdx.x; i < 4096; i += 256) {
    int kk = i >> 6, nn = i & 63;
    tile[kk][nn] = W[(size_t)(k0 + kk) * 256 + n0 + nn];
  }
  __syncthreads();
  for (int i = threadIdx.x; i < 4096; i += 256) {
    int nn = i >> 6, kk = i & 63;
    Wt[(size_t)(n0 + nn) * 256 + (k0 + kk)] = f2bf(tile[kk][nn]);
  }
}

// ------- x f32 -> bf16, pure streaming (exact cover: 2500 blocks * 512 thr * 8 elems) -------
__global__ __launch_bounds__(512) void k_cvt2(const float* __restrict__ x,
                                              unsigned short* __restrict__ xbf) {
  const int t = blockIdx.x * 512 + threadIdx.x;   // < 1,280,000
  const f4* in = (const f4*)(x + (size_t)t * 8);
  f4 v0 = in[0], v1 = in[1];
  u16x8 o;
  o[0] = f2bf(v0[0]); o[1] = f2bf(v0[1]); o[2] = f2bf(v0[2]); o[3] = f2bf(v0[3]);
  o[4] = f2bf(v1[0]); o[5] = f2bf(v1[1]); o[6] = f2bf(v1[2]); o[7] = f2bf(v1[3]);
  *(u16x8*)(xbf + (size_t)t * 8) = o;
}

// ---- GEMM v8 = v7 with the atomics bug fixed: per-head maxes accumulate in REGISTERS
// ---- across strips; 16 global atomicMax issued ONCE per wave at kernel end (never waited).
__global__ __launch_bounds__(256, 1) void k_gemm(const unsigned short* __restrict__ xbf,
                                                 const unsigned short* __restrict__ Wt,
                                                 const float* __restrict__ a,
                                                 float* __restrict__ wx,
                                                 unsigned short* __restrict__ ssbf,
                                                 unsigned short* __restrict__ sdbf,
                                                 unsigned int* __restrict__ mxbuf) {
  extern __shared__ char dyn2[];
  unsigned short* sBb = (unsigned short*)dyn2;   // [256 cols][32 chunks][8 bf16] = 131072 B
  char* sAb = dyn2 + 131072;                     // 4 waves * 8192 B
  const int tid = threadIdx.x;
  const int wv = tid >> 6;
  const int lane = tid & 63;
  const int fr = lane & 15;
  const int fg = lane >> 4;
  char* aw = sAb + wv * 8192;

  // stage B fully: 8192 16-B chunks; slot sc of col holds global chunk sc^(col&7)
#pragma unroll
  for (int it = 0; it < 32; ++it) {
    int q = it * 256 + tid;
    int col = q >> 5, sc = q & 31;
    gload_lds16(Wt + (size_t)col * 256 + ((sc ^ (col & 7)) << 3),
                (char*)sBb + it * 4096 + wv * 1024);
  }
  asm volatile("s_waitcnt vmcnt(0)" ::: "memory");
  __syncthreads();

  const float as0 = a[fr], as1 = a[16 + fr];
  const float ad0 = a[32 + fr], ad1 = a[48 + fr];
  const int gfr = (fr ^ (fr >> 2)) & 3;          // A read-side swizzle term
  unsigned rmx[16];                              // running ordf maxes (per-head, per-lane)
#pragma unroll
  for (int j = 0; j < 16; ++j) rmx[j] = 0u;

  for (int sp = blockIdx.x * 4 + wv; sp < 2500; sp += 1024) {
    // guard: prior strip's LDS reads done before overwriting A buffer
    asm volatile("s_waitcnt lgkmcnt(0)" ::: "memory");
    __builtin_amdgcn_sched_barrier(0);
    {
      const int r = lane >> 2;
      const int cc = (lane & 3) ^ ((r ^ (r >> 2)) & 3);
      const unsigned short* ag = xbf + (size_t)(sp * 16 + r) * 256 + cc * 8;
#pragma unroll
      for (int j = 0; j < 8; ++j)
        gload_lds16(ag + j * 32, aw + j * 1024);
    }
    asm volatile("s_waitcnt vmcnt(0)" ::: "memory");
    __builtin_amdgcn_sched_barrier(0);

    f4 acc[16] = {};
#pragma unroll
    for (int s0 = 0; s0 < 8; ++s0) {
      s8v afr = *(const s8v*)(aw + s0 * 1024 + (fr * 4 + (fg ^ gfr)) * 16);
#pragma unroll
      for (int n = 0; n < 16; ++n) {
        int col = n * 16 + fr;
        s8v bfr = *(const s8v*)((char*)sBb + col * 512 + (((4 * s0 + fg) ^ (fr & 7)) << 4));
        acc[n] = __builtin_amdgcn_mfma_f32_16x16x32_bf16(afr, bfr, acc[n], 0, 0, 0);
      }
    }
    // wx store: D[row][col], col = n*16+fr, row = fg*4+q
    const size_t rb = (size_t)sp * 16;
#pragma unroll
    for (int n = 0; n < 16; ++n) {
      int col = n * 16 + fr;
#pragma unroll
      for (int q = 0; q < 4; ++q)
        wx[(rb + fg * 4 + q) * 256 + col] = acc[n][q];
    }
    // fused scores: wave covers ALL 8 heads; head pair hp uses acc[4hp..4hp+3]
#pragma unroll
    for (int hp = 0; hp < 4; ++hp) {
#pragma unroll
      for (int q = 0; q < 4; ++q) {
        float p0 = acc[4 * hp][q] * as0 + acc[4 * hp + 1][q] * as1;
        float p1 = acc[4 * hp + 2][q] * as0 + acc[4 * hp + 3][q] * as1;
        float d0 = acc[4 * hp][q] * ad0 + acc[4 * hp + 1][q] * ad1;
        float d1 = acc[4 * hp + 2][q] * ad0 + acc[4 * hp + 3][q] * ad1;
#pragma unroll
        for (int m = 1; m <= 8; m <<= 1) {
          p0 += __shfl_xor(p0, m);
          p1 += __shfl_xor(p1, m);
          d0 += __shfl_xor(d0, m);
          d1 += __shfl_xor(d1, m);
        }
        rmx[2 * hp]     = max(rmx[2 * hp],     ordf(p0));
        rmx[2 * hp + 1] = max(rmx[2 * hp + 1], ordf(p1));
        rmx[8 + 2 * hp]     = max(rmx[8 + 2 * hp],     ordf(d0));
        rmx[8 + 2 * hp + 1] = max(rmx[8 + 2 * hp + 1], ordf(d1));
        if (fr == 0) {
          size_t row = rb + fg * 4 + q;
          ((unsigned*)ssbf)[row * 4 + hp] = (unsigned)f2bf(p0) | ((unsigned)f2bf(p1) << 16);
          ((unsigned*)sdbf)[row * 4 + hp] = (unsigned)f2bf(d0) | ((unsigned)f2bf(d1) << 16);
        }
      }
    }
  }
  // one cross-lane fold + ONE set of 16 global atomics per wave (fire-and-forget, at end)
#pragma unroll
  for (int j = 0; j < 16; ++j) {
    unsigned v = rmx[j];
    v = max(v, (unsigned)__shfl_xor((int)v, 16));
    v = max(v, (unsigned)__shfl_xor((int)v, 32));
    rmx[j] = v;
  }
  if (lane == 0) {
#pragma unroll
    for (int j = 0; j < 16; ++j)
      if (rmx[j]) atomicMax(&mxbuf[j], rmx[j]);
  }
}

// ---- LDS-privatized denom binning: block = (batch, head-half, src-range, slice) ----
__global__ __launch_bounds__(1024) void k_bin(const int* __restrict__ edge,
                                              const unsigned short* __restrict__ ssbf,
                                              const unsigned short* __restrict__ sdbf,
                                              const unsigned int* __restrict__ mxbuf,
                                              unsigned int* __restrict__ partial) {
  extern __shared__ unsigned int ldsu[];
  unsigned int* hist = ldsu;                      // [4][SEGR] u32
  uint2* stg = (uint2*)(ldsu + 4 * SEGR);         // [SEGR] 8-B src half-rows
  const int blk = blockIdx.x;                     // ((b*2+hq)*2+rq)*NSLICE + r
  const int r = blk & (NSLICE - 1);
  const int c = blk / NSLICE;
  const int rq = c & 1;
  const int hq = (c >> 1) & 1;
  const int b = c >> 2;
  const int tid = threadIdx.x;
  const int lo = rq * SEGR;
  for (int i = tid; i < 4 * SEGR; i += 1024) hist[i] = 0u;
  const unsigned short* ssb = ssbf + ((size_t)b * NN + lo) * 8 + hq * 4;
  for (int i = tid; i < SEGR; i += 1024) stg[i] = *(const uint2*)(ssb + (size_t)i * 8);
  __syncthreads();
  float MH[4];
#pragma unroll
  for (int j = 0; j < 4; ++j)
    MH[j] = fmaxf(unordf(mxbuf[hq * 4 + j]) + unordf(mxbuf[8 + hq * 4 + j]), 0.f);
  const int* eps = edge + (size_t)b * 2 * EE + r * ESL;
  const int* epd = eps + EE;
  const unsigned short* sdb = sdbf + (size_t)b * NN * 8 + hq * 4;
  for (int base = 0; base < ESL; base += UU * 1024) {
    int ls4[UU], dst4[UU];
    bool v4[UU];
#pragma unroll
    for (int u = 0; u < UU; ++u) {
      int i = base + tid + u * 1024;
      bool inb = i < ESL;
      int s = inb ? eps[i] : 0;
      dst4[u] = inb ? epd[i] : 0;
      int ls = s - lo;
      v4[u] = inb && ((unsigned)ls < (unsigned)SEGR);
      ls4[u] = ls;
    }
    uint2 du4[UU];
#pragma unroll
    for (int u = 0; u < UU; ++u)
      if (v4[u]) du4[u] = *(const uint2*)(sdb + (size_t)dst4[u] * 8);
#pragma unroll
    for (int u = 0; u < UU; ++u) {
      if (v4[u]) {
        uint2 su = stg[ls4[u]];
        float t0 = __uint_as_float(su.x << 16) + __uint_as_float(du4[u].x << 16);
        float t1 = __uint_as_float(su.x & 0xFFFF0000u) + __uint_as_float(du4[u].x & 0xFFFF0000u);
        float t2 = __uint_as_float(su.y << 16) + __uint_as_float(du4[u].y << 16);
        float t3 = __uint_as_float(su.y & 0xFFFF0000u) + __uint_as_float(du4[u].y & 0xFFFF0000u);
        t0 = t0 >= 0.f ? t0 : 0.2f * t0;
        t1 = t1 >= 0.f ? t1 : 0.2f * t1;
        t2 = t2 >= 0.f ? t2 : 0.2f * t2;
        t3 = t3 >= 0.f ? t3 : 0.2f * t3;
        atomicAdd(&hist[0 * SEGR + ls4[u]], (unsigned)(__expf(t0 - MH[0]) * SCALE + 0.5f));
        atomicAdd(&hist[1 * SEGR + ls4[u]], (unsigned)(__expf(t1 - MH[1]) * SCALE + 0.5f));
        atomicAdd(&hist[2 * SEGR + ls4[u]], (unsigned)(__expf(t2 - MH[2]) * SCALE + 0.5f));
        atomicAdd(&hist[3 * SEGR + ls4[u]], (unsigned)(__expf(t3 - MH[3]) * SCALE + 0.5f));
      }
    }
  }
  __syncthreads();
  f4* pout = (f4*)(partial + (size_t)blk * (4 * SEGR));
  const f4* lin = (const f4*)hist;
  for (int i = tid; i < SEGR; i += 1024) pout[i] = lin[i];
}

// ---- reduce NSLICE slice-partials (u32) -> denom (bf16 half-rows), exact int sums ----
__global__ __launch_bounds__(256) void k_reduce(const unsigned int* __restrict__ partial,
                                                unsigned short* __restrict__ dnbf) {
  const int t = blockIdx.x * 256 + threadIdx.x;   // BB*NHQ*NRQ*SEGR = 80000
  if (t >= BB * NHQ * NRQ * SEGR) return;
  const int ls = t % SEGR;
  const int c = t / SEGR;                         // ((b*2+hq)*2+rq)
  const unsigned int* pp = partial + (size_t)c * NSLICE * (4 * SEGR);
  unsigned long long s[4] = {0, 0, 0, 0};
#pragma unroll 4
  for (int r = 0; r < NSLICE; ++r)
#pragma unroll
    for (int h = 0; h < 4; ++h)
      s[h] += pp[(size_t)r * (4 * SEGR) + h * SEGR + ls];
  const int rq = c & 1, hq = (c >> 1) & 1, b = c >> 2;
  uint2 pk;
  pk.x = (unsigned)f2bf((float)s[0] * INVSC) | ((unsigned)f2bf((float)s[1] * INVSC) << 16);
  pk.y = (unsigned)f2bf((float)s[2] * INVSC) | ((unsigned)f2bf((float)s[3] * INVSC) << 16);
  *(uint2*)(dnbf + ((size_t)b * NN + rq * SEGR + ls) * 8 + hq * 4) = pk;
}

// ---------------- finalize: att = exp(el - M) / denom ----------------
__global__ __launch_bounds__(256) void k_fin(const int* __restrict__ edge,
                                             const unsigned short* __restrict__ ssbf,
                                             const unsigned short* __restrict__ sdbf,
                                             const unsigned short* __restrict__ dnbf,
                                             const unsigned int* __restrict__ mxbuf,
                                             float* __restrict__ att) {
  const int idx = blockIdx.x * 256 + threadIdx.x;
  const int b = idx / EE;
  const int e = idx - b * EE;
  const int src = edge[(size_t)b * 2 * EE + e];
  const int dst = edge[(size_t)b * 2 * EE + EE + e];
  const size_t seg = (size_t)b * NN + src;
  float MM[8];
#pragma unroll
  for (int j = 0; j < 8; ++j)
    MM[j] = fmaxf(unordf(mxbuf[j]) + unordf(mxbuf[8 + j]), 0.f);
  u16x8 ss = *(const u16x8*)(ssbf + seg * 8);
  u16x8 sd = *(const u16x8*)(sdbf + ((size_t)b * NN + dst) * 8);
  u16x8 dn = *(const u16x8*)(dnbf + seg * 8);
  f4 o0, o1;
#pragma unroll
  for (int j = 0; j < 4; ++j) {
    float t0 = bf2f(ss[j]) + bf2f(sd[j]);
    t0 = t0 >= 0.f ? t0 : 0.2f * t0;
    float t1 = bf2f(ss[4 + j]) + bf2f(sd[4 + j]);
    t1 = t1 >= 0.f ? t1 : 0.2f * t1;
    float n0 = __expf(t0 - MM[j]);
    float n1 = __expf(t1 - MM[4 + j]);
    o0[j] = n0 / fmaxf(bf2f(dn[j]), n0);
    o1[j] = n1 / fmaxf(bf2f(dn[4 + j]), n1);
  }
  f4* op = (f4*)(att + (size_t)idx * 8);
  op[0] = o0;
  op[1] = o1;
}

extern "C" void kernel_launch(void* const* d_in, const int* in_sizes, int n_in,
                              void* d_out, int out_size, void* d_ws, size_t ws_size,
                              hipStream_t stream) {
  const float* x = (const float*)d_in[0];
  const int* edge = (const int*)d_in[1];
  const float* W = (const float*)d_in[2];
  const float* a = (const float*)d_in[3];

  float* att = (float*)d_out;                       // (B,E,H) = 10,240,000 f32 = 40.96 MB
  float* wx = att + (size_t)BB * EE * HH;           // (B,N,256) = 10,240,000 f32

  // dead-region reuse inside att (40.96 MB):
  //   xbf     = att[5.12M .. 10.24M f32)  (20.48 MB) — written by k_cvt2, read by k_gemm
  //   partial = att[0 .. 5.12M f32)       (20.48 MB) — written by k_bin (after k_gemm)
  unsigned short* xbf = (unsigned short*)(att + 5120000);
  unsigned int* partial = (unsigned int*)att;

  char* ws = (char*)d_ws;
  unsigned short* Wt = (unsigned short*)ws;                 // 128 KiB
  unsigned short* ssbf = (unsigned short*)(ws + 131072);    // 320000 u16
  unsigned short* sdbf = ssbf + 320000;                     // 320000 u16
  unsigned short* dnbf = sdbf + 320000;                     // 320000 u16
  unsigned int* mxbuf = (unsigned int*)(dnbf + 320000);     // 16 u32

  const int gemmLds = 131072 + 4 * 8192;   // 160 KiB exactly
  hipFuncSetAttribute((const void*)k_gemm, hipFuncAttributeMaxDynamicSharedMemorySize, gemmLds);
  hipFuncSetAttribute((const void*)k_bin, hipFuncAttributeMaxDynamicSharedMemorySize,
                      4 * SEGR * 4 + SEGR * 8);

  k_transpose<<<dim3(4, 4), 256, 0, stream>>>(W, Wt, mxbuf);
  k_cvt2<<<2500, 512, 0, stream>>>(x, xbf);
  k_gemm<<<256, 256, gemmLds, stream>>>(xbf, Wt, a, wx, ssbf, sdbf, mxbuf);
  k_bin<<<BB * NHQ * NRQ * NSLICE, 1024, 4 * SEGR * 4 + SEGR * 8, stream>>>(edge, ssbf, sdbf, mxbuf, partial);
  k_reduce<<<(BB * NHQ * NRQ * SEGR + 255) / 256, 256, 0, stream>>>(partial, dnbf);
  k_fin<<<5000, 256, 0, stream>>>(edge, ssbf, sdbf, dnbf, mxbuf, att);
}

// Round 20
// 113.334 us; speedup vs baseline: 4.7274x; 2.4685x over previous
//
#include <hip/hip_runtime.h>
#include <hip/hip_bf16.h>

#define BB 4
#define NN 10000
#define EE 320000
#define HH 8
#define NHQ 2                 // head halves
#define NRQ 2                 // src ranges per batch
#define SEGR (NN / NRQ)       // 5000 segments per range
#define NSLICE 16             // edge slices -> grid = 4*2*2*16 = 256 = 1 block/CU
#define ESL (EE / NSLICE)     // 20000 edges per slice
#define UU 4                  // edges batched per thread (MLP)
#define SCALE 16777216.0f     // 2^24 fixed-point
#define INVSC (1.0f / 16777216.0f)
#define NGB 626               // k_gemm grid

typedef float f4 __attribute__((ext_vector_type(4)));
typedef short s8v __attribute__((ext_vector_type(8)));
typedef unsigned short u16x8 __attribute__((ext_vector_type(8)));

__device__ __forceinline__ unsigned short f2bf(float f) {
  unsigned int u = __float_as_uint(f);
  u += 0x7FFFu + ((u >> 16) & 1u);
  return (unsigned short)(u >> 16);
}
__device__ __forceinline__ float bf2f(unsigned short s) {
  return __uint_as_float(((unsigned int)s) << 16);
}
__device__ __forceinline__ unsigned int ordf(float f) {
  unsigned int u = __float_as_uint(f);
  return (u & 0x80000000u) ? ~u : (u | 0x80000000u);
}
__device__ __forceinline__ float unordf(unsigned int u) {
  unsigned int b = (u & 0x80000000u) ? (u & 0x7FFFFFFFu) : ~u;
  return __uint_as_float(b);
}
__device__ __forceinline__ void gload_lds16(const void* g, void* l) {
  __builtin_amdgcn_global_load_lds((const __attribute__((address_space(1))) void*)g,
                                   (__attribute__((address_space(3))) void*)l, 16, 0, 0);
}

// ------- W transpose + bf16 convert: Wt[n][k] = bf16(W[k][n]) -------
__global__ __launch_bounds__(256) void k_transpose(const float* __restrict__ W,
                                                   unsigned short* __restrict__ Wt) {
  __shared__ float tile[64][65];
  const int n0 = blockIdx.x * 64, k0 = blockIdx.y * 64;
  for (int i = threadIdx.x; i < 4096; i += 256) {
    int kk = i >> 6, nn = i & 63;
    tile[kk][nn] = W[(size_t)(k0 + kk) * 256 + n0 + nn];
  }
  __syncthreads();
  for (int i = threadIdx.x; i < 4096; i += 256) {
    int nn = i >> 6, kk = i & 63;
    Wt[(size_t)(n0 + nn) * 256 + (k0 + kk)] = f2bf(tile[kk][nn]);
  }
}

// ------- x f32 -> bf16, pure streaming -------
__global__ __launch_bounds__(512) void k_cvt2(const float* __restrict__ x,
                                              unsigned short* __restrict__ xbf) {
  const int t = blockIdx.x * 512 + threadIdx.x;   // < 1,280,000
  const f4* in = (const f4*)(x + (size_t)t * 8);
  f4 v0 = in[0], v1 = in[1];
  u16x8 o;
  o[0] = f2bf(v0[0]); o[1] = f2bf(v0[1]); o[2] = f2bf(v0[2]); o[3] = f2bf(v0[3]);
  o[4] = f2bf(v1[0]); o[5] = f2bf(v1[1]); o[6] = f2bf(v1[2]); o[7] = f2bf(v1[3]);
  *(u16x8*)(xbf + (size_t)t * 8) = o;
}

// ---- GEMM v9: 8 waves/block (2/SIMD), B-HALF staged (64 KB), ONE strip per wave,
// ---- single vmcnt drain, NO global atomics (per-block max -> plain store to pmx).
__global__ __launch_bounds__(512, 1) void k_gemm(const unsigned short* __restrict__ xbf,
                                                 const unsigned short* __restrict__ Wt,
                                                 const float* __restrict__ a,
                                                 float* __restrict__ wx,
                                                 unsigned short* __restrict__ ssbf,
                                                 unsigned short* __restrict__ sdbf,
                                                 unsigned int* __restrict__ pmx) {
  extern __shared__ char dyn2[];
  unsigned short* sBb = (unsigned short*)dyn2;   // [128 cols][32 chunks][8 bf16] = 65536 B
  char* sAb = dyn2 + 65536;                      // 8 waves * 8192 B
  unsigned int* lmx = (unsigned int*)(dyn2 + 131072);  // [16]
  const int tid = threadIdx.x;
  const int wv = tid >> 6;
  const int lane = tid & 63;
  const int fr = lane & 15;
  const int fg = lane >> 4;
  const int ch = blockIdx.x & 1;                 // col half
  const int sp = (blockIdx.x >> 1) * 8 + wv;     // this wave's strip
  char* aw = sAb + wv * 8192;
  if (tid < 16) lmx[tid] = 0u;

  // stage B half: 4096 chunks; slot sc of local col c holds global chunk sc^(c&7)
#pragma unroll
  for (int it = 0; it < 8; ++it) {
    int q = it * 512 + tid;
    int c = q >> 5, sc = q & 31;
    gload_lds16(Wt + (size_t)(ch * 128 + c) * 256 + ((sc ^ (c & 7)) << 3),
                (char*)sBb + it * 8192 + wv * 1024);
  }
  // stage this wave's A strip (8 KB)
  const bool live = sp < 2500;
  {
    const int r = lane >> 2;
    const int cc = (lane & 3) ^ ((r ^ (r >> 2)) & 3);
    const unsigned short* ag = xbf + (size_t)((live ? sp : 0) * 16 + r) * 256 + cc * 8;
#pragma unroll
    for (int j = 0; j < 8; ++j)
      gload_lds16(ag + j * 32, aw + j * 1024);
  }
  asm volatile("s_waitcnt vmcnt(0)" ::: "memory");
  __syncthreads();

  unsigned rmx[16];
#pragma unroll
  for (int j = 0; j < 16; ++j) rmx[j] = 0u;

  if (live) {
    const float as0 = a[fr], as1 = a[16 + fr];
    const float ad0 = a[32 + fr], ad1 = a[48 + fr];
    const int gfr = (fr ^ (fr >> 2)) & 3;
    f4 acc[8] = {};
#pragma unroll
    for (int s0 = 0; s0 < 8; ++s0) {
      s8v afr = *(const s8v*)(aw + s0 * 1024 + (fr * 4 + (fg ^ gfr)) * 16);
#pragma unroll
      for (int n = 0; n < 8; ++n) {
        int c = n * 16 + fr;     // local col
        s8v bfr = *(const s8v*)((char*)sBb + c * 512 + (((4 * s0 + fg) ^ (fr & 7)) << 4));
        acc[n] = __builtin_amdgcn_mfma_f32_16x16x32_bf16(afr, bfr, acc[n], 0, 0, 0);
      }
    }
    // wx store
    const size_t rb = (size_t)sp * 16;
#pragma unroll
    for (int n = 0; n < 8; ++n) {
      int col = ch * 128 + n * 16 + fr;
#pragma unroll
      for (int q = 0; q < 4; ++q)
        wx[(rb + fg * 4 + q) * 256 + col] = acc[n][q];
    }
    // fused scores: this wave covers heads ch*4 .. ch*4+3 (2 head-pairs)
#pragma unroll
    for (int jp = 0; jp < 2; ++jp) {
#pragma unroll
      for (int q = 0; q < 4; ++q) {
        float p0 = acc[4 * jp][q] * as0 + acc[4 * jp + 1][q] * as1;      // head ch*4+2jp
        float p1 = acc[4 * jp + 2][q] * as0 + acc[4 * jp + 3][q] * as1;  // head ch*4+2jp+1
        float d0 = acc[4 * jp][q] * ad0 + acc[4 * jp + 1][q] * ad1;
        float d1 = acc[4 * jp + 2][q] * ad0 + acc[4 * jp + 3][q] * ad1;
#pragma unroll
        for (int m = 1; m <= 8; m <<= 1) {
          p0 += __shfl_xor(p0, m);
          p1 += __shfl_xor(p1, m);
          d0 += __shfl_xor(d0, m);
          d1 += __shfl_xor(d1, m);
        }
        const int h0 = ch * 4 + 2 * jp;
        rmx[h0]     = max(rmx[h0],     ordf(p0));
        rmx[h0 + 1] = max(rmx[h0 + 1], ordf(p1));
        rmx[8 + h0]     = max(rmx[8 + h0],     ordf(d0));
        rmx[8 + h0 + 1] = max(rmx[8 + h0 + 1], ordf(d1));
        if (fr == 0) {
          size_t row = rb + fg * 4 + q;
          ((unsigned*)ssbf)[row * 4 + ch * 2 + jp] = (unsigned)f2bf(p0) | ((unsigned)f2bf(p1) << 16);
          ((unsigned*)sdbf)[row * 4 + ch * 2 + jp] = (unsigned)f2bf(d0) | ((unsigned)f2bf(d1) << 16);
        }
      }
    }
  }
  // block-level max via LDS only (no global atomics)
#pragma unroll
  for (int j = 0; j < 16; ++j) {
    unsigned v = rmx[j];
    v = max(v, (unsigned)__shfl_xor((int)v, 16));
    v = max(v, (unsigned)__shfl_xor((int)v, 32));
    rmx[j] = v;
  }
  if (lane == 0) {
#pragma unroll
    for (int j = 0; j < 16; ++j)
      if (rmx[j]) atomicMax(&lmx[j], rmx[j]);   // LDS atomic: cheap
  }
  __syncthreads();
  if (tid < 16) pmx[(size_t)blockIdx.x * 16 + tid] = lmx[tid];   // plain store
}

// ---- reduce per-block maxes (NGB x 16) -> mxbuf[16] ----
__global__ __launch_bounds__(256) void k_mxred(const unsigned int* __restrict__ pmx,
                                               unsigned int* __restrict__ mxbuf) {
  __shared__ unsigned int red[16][17];
  const int j = threadIdx.x & 15, g = threadIdx.x >> 4;
  unsigned v = 0;
  for (int i = g; i < NGB; i += 16) v = max(v, pmx[(size_t)i * 16 + j]);
  red[g][j] = v;
  __syncthreads();
  if (threadIdx.x < 16) {
    unsigned m = 0;
#pragma unroll
    for (int g2 = 0; g2 < 16; ++g2) m = max(m, red[g2][threadIdx.x]);
    mxbuf[threadIdx.x] = m;
  }
}

// ---- LDS-privatized denom binning: block = (batch, head-half, src-range, slice) ----
__global__ __launch_bounds__(1024) void k_bin(const int* __restrict__ edge,
                                              const unsigned short* __restrict__ ssbf,
                                              const unsigned short* __restrict__ sdbf,
                                              const unsigned int* __restrict__ mxbuf,
                                              unsigned int* __restrict__ partial) {
  extern __shared__ unsigned int ldsu[];
  unsigned int* hist = ldsu;                      // [4][SEGR] u32
  uint2* stg = (uint2*)(ldsu + 4 * SEGR);         // [SEGR] 8-B src half-rows
  const int blk = blockIdx.x;                     // ((b*2+hq)*2+rq)*NSLICE + r
  const int r = blk & (NSLICE - 1);
  const int c = blk / NSLICE;
  const int rq = c & 1;
  const int hq = (c >> 1) & 1;
  const int b = c >> 2;
  const int tid = threadIdx.x;
  const int lo = rq * SEGR;
  for (int i = tid; i < 4 * SEGR; i += 1024) hist[i] = 0u;
  const unsigned short* ssb = ssbf + ((size_t)b * NN + lo) * 8 + hq * 4;
  for (int i = tid; i < SEGR; i += 1024) stg[i] = *(const uint2*)(ssb + (size_t)i * 8);
  __syncthreads();
  float MH[4];
#pragma unroll
  for (int j = 0; j < 4; ++j)
    MH[j] = fmaxf(unordf(mxbuf[hq * 4 + j]) + unordf(mxbuf[8 + hq * 4 + j]), 0.f);
  const int* eps = edge + (size_t)b * 2 * EE + r * ESL;
  const int* epd = eps + EE;
  const unsigned short* sdb = sdbf + (size_t)b * NN * 8 + hq * 4;
  for (int base = 0; base < ESL; base += UU * 1024) {
    int ls4[UU], dst4[UU];
    bool v4[UU];
#pragma unroll
    for (int u = 0; u < UU; ++u) {
      int i = base + tid + u * 1024;
      bool inb = i < ESL;
      int s = inb ? eps[i] : 0;
      dst4[u] = inb ? epd[i] : 0;
      int ls = s - lo;
      v4[u] = inb && ((unsigned)ls < (unsigned)SEGR);
      ls4[u] = ls;
    }
    uint2 du4[UU];
#pragma unroll
    for (int u = 0; u < UU; ++u)
      if (v4[u]) du4[u] = *(const uint2*)(sdb + (size_t)dst4[u] * 8);
#pragma unroll
    for (int u = 0; u < UU; ++u) {
      if (v4[u]) {
        uint2 su = stg[ls4[u]];
        float t0 = __uint_as_float(su.x << 16) + __uint_as_float(du4[u].x << 16);
        float t1 = __uint_as_float(su.x & 0xFFFF0000u) + __uint_as_float(du4[u].x & 0xFFFF0000u);
        float t2 = __uint_as_float(su.y << 16) + __uint_as_float(du4[u].y << 16);
        float t3 = __uint_as_float(su.y & 0xFFFF0000u) + __uint_as_float(du4[u].y & 0xFFFF0000u);
        t0 = t0 >= 0.f ? t0 : 0.2f * t0;
        t1 = t1 >= 0.f ? t1 : 0.2f * t1;
        t2 = t2 >= 0.f ? t2 : 0.2f * t2;
        t3 = t3 >= 0.f ? t3 : 0.2f * t3;
        atomicAdd(&hist[0 * SEGR + ls4[u]], (unsigned)(__expf(t0 - MH[0]) * SCALE + 0.5f));
        atomicAdd(&hist[1 * SEGR + ls4[u]], (unsigned)(__expf(t1 - MH[1]) * SCALE + 0.5f));
        atomicAdd(&hist[2 * SEGR + ls4[u]], (unsigned)(__expf(t2 - MH[2]) * SCALE + 0.5f));
        atomicAdd(&hist[3 * SEGR + ls4[u]], (unsigned)(__expf(t3 - MH[3]) * SCALE + 0.5f));
      }
    }
  }
  __syncthreads();
  f4* pout = (f4*)(partial + (size_t)blk * (4 * SEGR));
  const f4* lin = (const f4*)hist;
  for (int i = tid; i < SEGR; i += 1024) pout[i] = lin[i];
}

// ---- reduce NSLICE slice-partials (u32) -> denom (bf16 half-rows), exact int sums ----
__global__ __launch_bounds__(256) void k_reduce(const unsigned int* __restrict__ partial,
                                                unsigned short* __restrict__ dnbf) {
  const int t = blockIdx.x * 256 + threadIdx.x;   // BB*NHQ*NRQ*SEGR = 80000
  if (t >= BB * NHQ * NRQ * SEGR) return;
  const int ls = t % SEGR;
  const int c = t / SEGR;                         // ((b*2+hq)*2+rq)
  const unsigned int* pp = partial + (size_t)c * NSLICE * (4 * SEGR);
  unsigned long long s[4] = {0, 0, 0, 0};
#pragma unroll 4
  for (int r = 0; r < NSLICE; ++r)
#pragma unroll
    for (int h = 0; h < 4; ++h)
      s[h] += pp[(size_t)r * (4 * SEGR) + h * SEGR + ls];
  const int rq = c & 1, hq = (c >> 1) & 1, b = c >> 2;
  uint2 pk;
  pk.x = (unsigned)f2bf((float)s[0] * INVSC) | ((unsigned)f2bf((float)s[1] * INVSC) << 16);
  pk.y = (unsigned)f2bf((float)s[2] * INVSC) | ((unsigned)f2bf((float)s[3] * INVSC) << 16);
  *(uint2*)(dnbf + ((size_t)b * NN + rq * SEGR + ls) * 8 + hq * 4) = pk;
}

// ---------------- finalize: att = exp(el - M) / denom ----------------
__global__ __launch_bounds__(256) void k_fin(const int* __restrict__ edge,
                                             const unsigned short* __restrict__ ssbf,
                                             const unsigned short* __restrict__ sdbf,
                                             const unsigned short* __restrict__ dnbf,
                                             const unsigned int* __restrict__ mxbuf,
                                             float* __restrict__ att) {
  const int idx = blockIdx.x * 256 + threadIdx.x;
  const int b = idx / EE;
  const int e = idx - b * EE;
  const int src = edge[(size_t)b * 2 * EE + e];
  const int dst = edge[(size_t)b * 2 * EE + EE + e];
  const size_t seg = (size_t)b * NN + src;
  float MM[8];
#pragma unroll
  for (int j = 0; j < 8; ++j)
    MM[j] = fmaxf(unordf(mxbuf[j]) + unordf(mxbuf[8 + j]), 0.f);
  u16x8 ss = *(const u16x8*)(ssbf + seg * 8);
  u16x8 sd = *(const u16x8*)(sdbf + ((size_t)b * NN + dst) * 8);
  u16x8 dn = *(const u16x8*)(dnbf + seg * 8);
  f4 o0, o1;
#pragma unroll
  for (int j = 0; j < 4; ++j) {
    float t0 = bf2f(ss[j]) + bf2f(sd[j]);
    t0 = t0 >= 0.f ? t0 : 0.2f * t0;
    float t1 = bf2f(ss[4 + j]) + bf2f(sd[4 + j]);
    t1 = t1 >= 0.f ? t1 : 0.2f * t1;
    float n0 = __expf(t0 - MM[j]);
    float n1 = __expf(t1 - MM[4 + j]);
    o0[j] = n0 / fmaxf(bf2f(dn[j]), n0);
    o1[j] = n1 / fmaxf(bf2f(dn[4 + j]), n1);
  }
  f4* op = (f4*)(att + (size_t)idx * 8);
  op[0] = o0;
  op[1] = o1;
}

extern "C" void kernel_launch(void* const* d_in, const int* in_sizes, int n_in,
                              void* d_out, int out_size, void* d_ws, size_t ws_size,
                              hipStream_t stream) {
  const float* x = (const float*)d_in[0];
  const int* edge = (const int*)d_in[1];
  const float* W = (const float*)d_in[2];
  const float* a = (const float*)d_in[3];

  float* att = (float*)d_out;                       // (B,E,H) = 10,240,000 f32 = 40.96 MB
  float* wx = att + (size_t)BB * EE * HH;           // (B,N,256) = 10,240,000 f32

  // dead-region reuse inside att (40.96 MB):
  //   xbf     = att[5.12M .. 10.24M f32)  (20.48 MB) — written by k_cvt2, read by k_gemm
  //   partial = att[0 .. 5.12M f32)       (20.48 MB) — written by k_bin (after k_gemm)
  unsigned short* xbf = (unsigned short*)(att + 5120000);
  unsigned int* partial = (unsigned int*)att;

  char* ws = (char*)d_ws;
  unsigned short* Wt = (unsigned short*)ws;                 // 128 KiB
  unsigned short* ssbf = (unsigned short*)(ws + 131072);    // 320000 u16
  unsigned short* sdbf = ssbf + 320000;                     // 320000 u16
  unsigned short* dnbf = sdbf + 320000;                     // 320000 u16
  unsigned int* mxbuf = (unsigned int*)(dnbf + 320000);     // 16 u32
  unsigned int* pmx = mxbuf + 16;                           // NGB*16 u32 = 40 KB

  const int gemmLds = 131072 + 64;   // 64K B-half + 64K A (8 waves) + lmx
  hipFuncSetAttribute((const void*)k_gemm, hipFuncAttributeMaxDynamicSharedMemorySize, gemmLds);
  hipFuncSetAttribute((const void*)k_bin, hipFuncAttributeMaxDynamicSharedMemorySize,
                      4 * SEGR * 4 + SEGR * 8);

  k_transpose<<<dim3(4, 4), 256, 0, stream>>>(W, Wt);
  k_cvt2<<<2500, 512, 0, stream>>>(x, xbf);
  k_gemm<<<NGB, 512, gemmLds, stream>>>(xbf, Wt, a, wx, ssbf, sdbf, pmx);
  k_mxred<<<1, 256, 0, stream>>>(pmx, mxbuf);
  k_bin<<<BB * NHQ * NRQ * NSLICE, 1024, 4 * SEGR * 4 + SEGR * 8, stream>>>(edge, ssbf, sdbf, mxbuf, partial);
  k_reduce<<<(BB * NHQ * NRQ * SEGR + 255) / 256, 256, 0, stream>>>(partial, dnbf);
  k_fin<<<5000, 256, 0, stream>>>(edge, ssbf, sdbf, dnbf, mxbuf, att);
}